// Round 5
// baseline (514.689 us; speedup 1.0000x reference)
//
#include <hip/hip_runtime.h>

// Problem constants (match reference)
constexpr int N  = 100000;   // nodes
constexpr int E  = 1600000;  // edges
constexpr int H  = 128;      // hidden
constexpr int NB = 4096;     // root pairs
constexpr int HOPS = 3;

// Transposed converted-weight buffer (element offsets into whi/wlo ushort arrays)
// All stored n-major: Bt[n][k]
constexpr int WOFF_L1  = 0;                      // [128 n][256 k] lin1_W^T
constexpr int WOFF_GAT = 32768;                  // 3 x [128][128] gat_W^T
constexpr int WOFF_CAT = 81920;                  // 3 x [512 n][384 k] [Wih;Whh]^T
constexpr int WOFF_L2  = 671744;                 // [128][128] lin2_W^T
constexpr int WTOT     = 688128;

// ---------------- workspace layout (byte offsets, 256B aligned) ---------------
constexpr size_t ALIGN = 256;
constexpr size_t alup(size_t x) { return (x + ALIGN - 1) & ~(ALIGN - 1); }

constexpr size_t OFF_X       = 0;                                        // [N,128] f32
constexpr size_t OFF_SSRC    = alup(OFF_X + (size_t)N * H * 4);          // [3][N] f32
constexpr size_t OFF_SDST    = alup(OFF_SSRC + (size_t)3 * N * 4);       // [3][N] f32
constexpr size_t OFF_WVEC    = alup(OFF_SDST + (size_t)3 * N * 4);       // [6][128] f32
constexpr size_t OFF_SELMAP  = alup(OFF_WVEC + 6 * H * 4);               // [N] int
constexpr size_t OFF_NODELST = alup(OFF_SELMAP + (size_t)N * 4);         // [4096] int
constexpr size_t OFF_CNT     = alup(OFF_NODELST + NB * 4);               // [2] int
constexpr size_t OFF_DEG     = alup(OFF_CNT + 256);                      // [4096] int
constexpr size_t OFF_OFFS    = alup(OFF_DEG + NB * 4);                   // [4097] int
constexpr size_t OFF_CURSOR  = alup(OFF_OFFS + (NB + 1) * 4);            // [4096] int
constexpr size_t OFF_ESORT   = alup(OFF_CURSOR + NB * 4);                // [E] int
constexpr size_t OFF_AGGXH   = alup(OFF_ESORT + (size_t)E * 4);          // [3][4096][128] us
constexpr size_t OFF_AGGXL   = alup(OFF_AGGXH + (size_t)3 * NB * H * 2);
constexpr size_t OFF_XSH     = alup(OFF_AGGXL + (size_t)3 * NB * H * 2); // [4096][128] us
constexpr size_t OFF_XSL     = alup(OFF_XSH + (size_t)NB * H * 2);
constexpr size_t OFF_HTH     = alup(OFF_XSL + (size_t)NB * H * 2);       // htmp pair
constexpr size_t OFF_HTL     = alup(OFF_HTH + (size_t)NB * H * 2);
constexpr size_t OFF_HH      = alup(OFF_HTL + (size_t)NB * H * 2);       // h pair
constexpr size_t OFF_HL      = alup(OFF_HH + (size_t)NB * H * 2);
constexpr size_t OFF_CBUF    = alup(OFF_HL + (size_t)NB * H * 2);        // [4096][128] f32
constexpr size_t OFF_L2OUT   = alup(OFF_CBUF + (size_t)NB * H * 4);      // [4096][128] f32
constexpr size_t OFF_WHI     = alup(OFF_L2OUT + (size_t)NB * H * 4);     // [WTOT] us
constexpr size_t OFF_WLO     = alup(OFF_WHI + (size_t)WTOT * 2);         // [WTOT] us

__device__ __forceinline__ float lrelu(float v) { return v > 0.f ? v : 0.2f * v; }
__device__ __forceinline__ float sigmoidf_(float v) { return 1.f / (1.f + __expf(-v)); }

// RNE bf16 (weights / producers — off the hot path)
__device__ __forceinline__ unsigned short f2bf(float f) {
  unsigned u = __float_as_uint(f);
  unsigned r = (u + 0x7FFFu + ((u >> 16) & 1u)) >> 16;
  return (unsigned short)r;
}
__device__ __forceinline__ float bf2f(unsigned short h) {
  return __uint_as_float((unsigned)h << 16);
}
__device__ __forceinline__ void split_rne(float f, unsigned short& hi, unsigned short& lo) {
  unsigned short hh = f2bf(f);
  hi = hh;
  lo = f2bf(f - bf2f(hh));
}
// 4-op truncation split (hot path, lin1 A conversion): hi=trunc16, lo exact residual
// NOTE: returns via scalar temporaries — vector elements can't bind to refs.
__device__ __forceinline__ void split_trunc(float f, short* hi, short* lo) {
  unsigned u = __float_as_uint(f);
  *hi = (short)(u >> 16);
  float r = f - __uint_as_float(u & 0xFFFF0000u);
  *lo = (short)(__float_as_uint(r) >> 16);
}

typedef short bf16x8 __attribute__((ext_vector_type(8)));
typedef float f32x4  __attribute__((ext_vector_type(4)));

// ---------------- tiny setup kernels -----------------------------------------

__global__ void wvec_kernel(const float* __restrict__ gat_W,
                            const float* __restrict__ a_src,
                            const float* __restrict__ a_dst,
                            float* __restrict__ wvec) {
  int i = blockIdx.x >> 1, which = blockIdx.x & 1;
  int k = threadIdx.x;
  __shared__ float av[H];
  av[k] = which ? a_dst[i * H + k] : a_src[i * H + k];
  __syncthreads();
  const float* Wr = gat_W + (size_t)i * H * H + (size_t)k * H;
  float s = 0.f;
  #pragma unroll 8
  for (int j = 0; j < H; j++) s = fmaf(Wr[j], av[j], s);
  wvec[(i * 2 + which) * H + k] = s;
}

__global__ void mark_roots(const int* __restrict__ root, const int* __restrict__ aggp,
                           int* __restrict__ sel_map) {
  int b = blockIdx.x * 256 + threadIdx.x;
  if (b >= NB) return;
  int node = root[2 * b + (aggp[0] ? 0 : 1)];
  sel_map[node] = -2;   // benign race: same value
}

__global__ void assign_ids(int* __restrict__ sel_map, int* __restrict__ node_list,
                           int* __restrict__ cnt) {
  int n = blockIdx.x * 256 + threadIdx.x;
  if (n >= N) return;
  if (sel_map[n] == -2) {
    int c = atomicAdd(cnt, 1);   // wave-aggregated by LLVM
    sel_map[n] = c;
    node_list[c] = n;
  }
}

// ---------------- weight conversion fp32 -> TRANSPOSED bf16 hi/lo -------------
__global__ void convert_weights(const float* __restrict__ lin1_W,
                                const float* __restrict__ gat_W,
                                const float* __restrict__ Wih,
                                const float* __restrict__ Whh,
                                const float* __restrict__ lin2_W,
                                unsigned short* __restrict__ whi,
                                unsigned short* __restrict__ wlo) {
  int idx = blockIdx.x * 256 + threadIdx.x;
  if (idx >= WTOT) return;
  float v;
  if (idx < WOFF_GAT) {                      // L1t [128 n][256 k]
    int n = idx >> 8, k = idx & 255;
    v = lin1_W[k * 128 + n];
  } else if (idx < WOFF_CAT) {               // GATt 3 x [128 n][128 k]
    int r = idx - WOFF_GAT;
    int hop = r >> 14, q = r & 16383;
    int n = q >> 7, k = q & 127;
    v = gat_W[hop * 16384 + k * 128 + n];
  } else if (idx < WOFF_L2) {                // CATt 3 x [512 n][384 k]
    int r = idx - WOFF_CAT;
    int hop = r / 196608, q = r % 196608;
    int n = q / 384, k = q % 384;
    v = (k < 256) ? Wih[hop * 131072 + k * 512 + n]
                  : Whh[hop * 65536 + (k - 256) * 512 + n];
  } else {                                   // L2t [128 n][128 k]
    int r = idx - WOFF_L2;
    int n = r >> 7, k = r & 127;
    v = lin2_W[k * 128 + n];
  }
  unsigned short hh, ll;
  split_rne(v, hh, ll);
  whi[idx] = hh;
  wlo[idx] = ll;
}

// ---------------- lin1: fp32-A split-bf16 MFMA GEMM, full-width ----------------
// x[M][128] = [a0|a1][M][256] @ B + bias. Block = 4 waves x 32 rows = 128 rows,
// full 128 cols (A converted exactly once). B fragments straight from L2
// (transposed bf16 weights, 64B-contiguous quad reads). No LDS, no barriers.
__global__ __launch_bounds__(256)
void gemm_lin1(const float* __restrict__ a0, const float* __restrict__ a1,
               const unsigned short* __restrict__ Bth,
               const unsigned short* __restrict__ Btl,
               const float* __restrict__ bias, float* __restrict__ Cc, int M) {
  const int t = threadIdx.x, lane = t & 63, wave = t >> 6;
  const int nl = lane & 15, quad = lane >> 4;
  const int rt = blockIdx.x * 128 + wave * 32;
  const float* asegs[2] = {a0, a1};

  f32x4 acc[2][8];
  #pragma unroll
  for (int i = 0; i < 2; i++)
    #pragma unroll
    for (int j = 0; j < 8; j++) acc[i][j] = (f32x4){0.f, 0.f, 0.f, 0.f};

  #pragma unroll
  for (int kt = 0; kt < 8; kt++) {
    const float* A = asegs[kt >> 2];
    const int kk = (kt & 3) * 32 + quad * 8;
    bf16x8 ahi[2], alo[2];
    #pragma unroll
    for (int i = 0; i < 2; i++) {
      int row = rt + i * 16 + nl;
      float4 v0 = make_float4(0.f, 0.f, 0.f, 0.f), v1 = v0;
      if (row < M) {
        const float* p = A + (size_t)row * H + kk;
        v0 = *(const float4*)p;
        v1 = *(const float4*)(p + 4);
      }
      float af[8] = {v0.x, v0.y, v0.z, v0.w, v1.x, v1.y, v1.z, v1.w};
      #pragma unroll
      for (int j = 0; j < 8; j++) {
        short h_, l_;
        split_trunc(af[j], &h_, &l_);
        ahi[i][j] = h_;
        alo[i][j] = l_;
      }
    }
    #pragma unroll
    for (int j = 0; j < 8; j++) {
      size_t boff = (size_t)(j * 16 + nl) * 256 + kt * 32 + quad * 8;
      bf16x8 bhi = *(const bf16x8*)(Bth + boff);
      bf16x8 blo = *(const bf16x8*)(Btl + boff);
      #pragma unroll
      for (int i = 0; i < 2; i++) {
        acc[i][j] = __builtin_amdgcn_mfma_f32_16x16x32_bf16(ahi[i], bhi, acc[i][j], 0, 0, 0);
        acc[i][j] = __builtin_amdgcn_mfma_f32_16x16x32_bf16(ahi[i], blo, acc[i][j], 0, 0, 0);
        acc[i][j] = __builtin_amdgcn_mfma_f32_16x16x32_bf16(alo[i], bhi, acc[i][j], 0, 0, 0);
      }
    }
  }
  float bv[8];
  #pragma unroll
  for (int j = 0; j < 8; j++) bv[j] = bias[j * 16 + nl];
  #pragma unroll
  for (int i = 0; i < 2; i++)
    #pragma unroll
    for (int r = 0; r < 4; r++) {
      int row = rt + i * 16 + quad * 4 + r;
      if (row < M) {
        float* cr = Cc + (size_t)row * H;
        #pragma unroll
        for (int j = 0; j < 8; j++) cr[j * 16 + nl] = acc[i][j][r] + bv[j];
      }
    }
}

// ---------------- small GEMM: pre-converted bf16-pair A, no LDS ---------------
// C[M][Nn] = concat(A segs [M][128] bf16 hi/lo) @ Bt^T + bias.
// Block = 4 waves x 16 rows = 64 rows x 128 cols. out: fp32 or bf16-pair (+tanh).
__global__ __launch_bounds__(256)
void gemm_small(const unsigned short* __restrict__ ah0, const unsigned short* __restrict__ al0,
                const unsigned short* __restrict__ Bth, const unsigned short* __restrict__ Btl,
                const float* __restrict__ bias, float* __restrict__ outf,
                unsigned short* __restrict__ outh, unsigned short* __restrict__ outl,
                int Nn, int act) {
  const int t = threadIdx.x, lane = t & 63, wave = t >> 6;
  const int nl = lane & 15, quad = lane >> 4;
  const int n0 = blockIdx.x * 128;
  const int rt = blockIdx.y * 64 + wave * 16;

  f32x4 acc[8];
  #pragma unroll
  for (int j = 0; j < 8; j++) acc[j] = (f32x4){0.f, 0.f, 0.f, 0.f};

  #pragma unroll
  for (int kt = 0; kt < 4; kt++) {
    int kk = kt * 32 + quad * 8;
    size_t aoff = (size_t)(rt + nl) * 128 + kk;
    bf16x8 ahi = *(const bf16x8*)(ah0 + aoff);
    bf16x8 alo = *(const bf16x8*)(al0 + aoff);
    #pragma unroll
    for (int j = 0; j < 8; j++) {
      size_t boff = (size_t)(n0 + j * 16 + nl) * 128 + kk;
      bf16x8 bhi = *(const bf16x8*)(Bth + boff);
      bf16x8 blo = *(const bf16x8*)(Btl + boff);
      acc[j] = __builtin_amdgcn_mfma_f32_16x16x32_bf16(ahi, bhi, acc[j], 0, 0, 0);
      acc[j] = __builtin_amdgcn_mfma_f32_16x16x32_bf16(ahi, blo, acc[j], 0, 0, 0);
      acc[j] = __builtin_amdgcn_mfma_f32_16x16x32_bf16(alo, bhi, acc[j], 0, 0, 0);
    }
  }
  float bv[8];
  #pragma unroll
  for (int j = 0; j < 8; j++) bv[j] = bias[n0 + j * 16 + nl];
  #pragma unroll
  for (int r = 0; r < 4; r++) {
    int row = rt + quad * 4 + r;
    #pragma unroll
    for (int j = 0; j < 8; j++) {
      float v = acc[j][r] + bv[j];
      if (act) v = tanhf(v);
      int col = n0 + j * 16 + nl;
      if (outf) {
        outf[(size_t)row * Nn + col] = v;
      } else {
        unsigned short hh, ll;
        split_rne(v, hh, ll);
        outh[(size_t)row * Nn + col] = hh;
        outl[(size_t)row * Nn + col] = ll;
      }
    }
  }
}

// ---------------- fused gates-GEMM + LSTM step --------------------------------
// Block = 64 rows x 32 features x 4 gates (128 cols of the permuted gate matrix).
// A segs: htmp, xs-or-h, h (bf16 pairs). Reads/writes cbuf, writes h pair.
// Row-local read/write of h: block reads only its own rows -> no cross-block hazard.
__global__ __launch_bounds__(256)
void lstm_fused(const unsigned short* __restrict__ ah0, const unsigned short* __restrict__ al0,
                const unsigned short* __restrict__ ah1, const unsigned short* __restrict__ al1,
                const unsigned short* __restrict__ ah2, const unsigned short* __restrict__ al2,
                const unsigned short* __restrict__ Bth, const unsigned short* __restrict__ Btl,
                const float* __restrict__ bias,
                float* __restrict__ cbuf, unsigned short* __restrict__ hh,
                unsigned short* __restrict__ hl) {
  const int t = threadIdx.x, lane = t & 63, wave = t >> 6;
  const int nl = lane & 15, quad = lane >> 4;
  const int f0 = blockIdx.x * 32;          // 32 features per block
  const int rt = blockIdx.y * 64 + wave * 16;
  const unsigned short* ahs[3] = {ah0, ah1, ah2};
  const unsigned short* als[3] = {al0, al1, al2};

  f32x4 acc[8];  // j = ftile*4 + gate
  #pragma unroll
  for (int j = 0; j < 8; j++) acc[j] = (f32x4){0.f, 0.f, 0.f, 0.f};

  for (int kt = 0; kt < 12; kt++) {
    int seg = kt >> 2, kk = (kt & 3) * 32 + quad * 8;
    size_t aoff = (size_t)(rt + nl) * 128 + kk;
    bf16x8 ahi = *(const bf16x8*)(ahs[seg] + aoff);
    bf16x8 alo = *(const bf16x8*)(als[seg] + aoff);
    int kg = kt * 32 + quad * 8;
    #pragma unroll
    for (int j = 0; j < 8; j++) {
      int col = (j & 3) * 128 + f0 + (j >> 2) * 16 + nl;
      size_t boff = (size_t)col * 384 + kg;
      bf16x8 bhi = *(const bf16x8*)(Bth + boff);
      bf16x8 blo = *(const bf16x8*)(Btl + boff);
      acc[j] = __builtin_amdgcn_mfma_f32_16x16x32_bf16(ahi, bhi, acc[j], 0, 0, 0);
      acc[j] = __builtin_amdgcn_mfma_f32_16x16x32_bf16(ahi, blo, acc[j], 0, 0, 0);
      acc[j] = __builtin_amdgcn_mfma_f32_16x16x32_bf16(alo, bhi, acc[j], 0, 0, 0);
    }
  }
  float bv[8];
  #pragma unroll
  for (int j = 0; j < 8; j++) bv[j] = bias[(j & 3) * 128 + f0 + (j >> 2) * 16 + nl];
  #pragma unroll
  for (int ft = 0; ft < 2; ft++) {
    #pragma unroll
    for (int r = 0; r < 4; r++) {
      int row = rt + quad * 4 + r;
      int f = f0 + ft * 16 + nl;
      float gi = acc[ft * 4 + 0][r] + bv[ft * 4 + 0];
      float gf = acc[ft * 4 + 1][r] + bv[ft * 4 + 1];
      float gg = acc[ft * 4 + 2][r] + bv[ft * 4 + 2];
      float go = acc[ft * 4 + 3][r] + bv[ft * 4 + 3];
      size_t id = (size_t)row * H + f;
      float cp = cbuf[id];
      float cn = sigmoidf_(gf) * cp + sigmoidf_(gi) * tanhf(gg);
      float hn = sigmoidf_(go) * tanhf(cn);
      cbuf[id] = cn;
      unsigned short vh, vl;
      split_rne(hn, vh, vl);
      hh[id] = vh;
      hl[id] = vl;
    }
  }
}

// ---------------- attention score vectors: s = x @ wvec ----------------------
__global__ __launch_bounds__(256)
void score_kernel(const float* __restrict__ x, const float* __restrict__ wvec,
                  float* __restrict__ s_src, float* __restrict__ s_dst) {
  int wv = blockIdx.x * 4 + (threadIdx.x >> 6);
  int lane = threadIdx.x & 63;
  if (wv >= N) return;
  float2 v = *(const float2*)(x + (size_t)wv * H + lane * 2);
  float acc[6];
  #pragma unroll
  for (int i = 0; i < 6; i++) {
    float2 w = *(const float2*)(wvec + i * H + lane * 2);
    acc[i] = v.x * w.x + v.y * w.y;
  }
  #pragma unroll
  for (int off = 32; off > 0; off >>= 1)
    #pragma unroll
    for (int i = 0; i < 6; i++) acc[i] += __shfl_down(acc[i], off);
  if (lane == 0) {
    #pragma unroll
    for (int i = 0; i < 3; i++) {
      s_src[i * N + wv] = acc[2 * i + 0];
      s_dst[i * N + wv] = acc[2 * i + 1];
    }
  }
}

// ---------------- edge CSR by destination ------------------------------------
__global__ void count_edges(const int* __restrict__ ei, const int* __restrict__ sel_map,
                            int* __restrict__ deg) {
  int e = blockIdx.x * 256 + threadIdx.x;
  if (e >= E) return;
  int d = sel_map[ei[E + e]];
  if (d >= 0) atomicAdd(&deg[d], 1);
}

__global__ __launch_bounds__(1024)
void scan_kernel(const int* __restrict__ deg, int* __restrict__ offs) {
  __shared__ int part[1024];
  int t = threadIdx.x;
  int base = t * 4;
  int v0 = deg[base], v1 = deg[base + 1], v2 = deg[base + 2], v3 = deg[base + 3];
  int s = v0 + v1 + v2 + v3;
  part[t] = s;
  __syncthreads();
  for (int off = 1; off < 1024; off <<= 1) {
    int tmp = (t >= off) ? part[t - off] : 0;
    __syncthreads();
    part[t] += tmp;
    __syncthreads();
  }
  int run = part[t] - s;
  offs[base] = run; run += v0;
  offs[base + 1] = run; run += v1;
  offs[base + 2] = run; run += v2;
  offs[base + 3] = run; run += v3;
  if (t == 1023) offs[NB] = part[1023];
}

__global__ void scatter_edges2(const int* __restrict__ ei, const int* __restrict__ sel_map,
                               const int* __restrict__ offs, int* __restrict__ cursor,
                               int* __restrict__ es_sorted) {
  int e = blockIdx.x * 256 + threadIdx.x;
  if (e >= E) return;
  int d = sel_map[ei[E + e]];
  if (d >= 0) {
    int p = atomicAdd(&cursor[d], 1);
    es_sorted[offs[d] + p] = ei[e];
  }
}

// ---------------- per-destination GAT softmax aggregation ---------------------
// Writes aggx + xs directly as bf16 hi/lo pairs (consumed only by MFMA GEMMs).
__global__ __launch_bounds__(128)
void gat_node_kernel(const int* __restrict__ node_list, const int* __restrict__ cntp,
                     const int* __restrict__ offs, const int* __restrict__ es_sorted,
                     const float* __restrict__ x, const float* __restrict__ s_src,
                     const float* __restrict__ s_dst,
                     unsigned short* __restrict__ aggxh, unsigned short* __restrict__ aggxl,
                     unsigned short* __restrict__ xsh, unsigned short* __restrict__ xsl) {
  int c = blockIdx.x;
  if (c >= cntp[0]) return;
  int t = threadIdx.x;
  int n = node_list[c];
  {
    float xv = x[(size_t)n * H + t];
    unsigned short vh, vl;
    split_rne(xv, vh, vl);
    xsh[(size_t)c * H + t] = vh;
    xsl[(size_t)c * H + t] = vl;
  }
  float sd0 = s_dst[0 * N + n], sd1 = s_dst[1 * N + n], sd2 = s_dst[2 * N + n];
  int e0 = offs[c], e1 = offs[c + 1];
  float m0 = -1e30f, m1 = -1e30f, m2 = -1e30f;
  for (int e = e0 + t; e < e1; e += 128) {
    int s = es_sorted[e];
    m0 = fmaxf(m0, lrelu(s_src[0 * N + s] + sd0));
    m1 = fmaxf(m1, lrelu(s_src[1 * N + s] + sd1));
    m2 = fmaxf(m2, lrelu(s_src[2 * N + s] + sd2));
  }
  __shared__ float red[3][128];
  red[0][t] = m0; red[1][t] = m1; red[2][t] = m2;
  __syncthreads();
  for (int s2 = 64; s2 > 0; s2 >>= 1) {
    if (t < s2) {
      red[0][t] = fmaxf(red[0][t], red[0][t + s2]);
      red[1][t] = fmaxf(red[1][t], red[1][t + s2]);
      red[2][t] = fmaxf(red[2][t], red[2][t + s2]);
    }
    __syncthreads();
  }
  m0 = red[0][0]; m1 = red[1][0]; m2 = red[2][0];
  float u0 = 0.f, u1 = 0.f, u2 = 0.f, z0 = 0.f, z1 = 0.f, z2 = 0.f;
  for (int e = e0; e < e1; e++) {
    int s = es_sorted[e];
    float xs = x[(size_t)s * H + t];
    float ex0 = __expf(lrelu(s_src[0 * N + s] + sd0) - m0);
    float ex1 = __expf(lrelu(s_src[1 * N + s] + sd1) - m1);
    float ex2 = __expf(lrelu(s_src[2 * N + s] + sd2) - m2);
    z0 += ex0; z1 += ex1; z2 += ex2;
    u0 = fmaf(ex0, xs, u0); u1 = fmaf(ex1, xs, u1); u2 = fmaf(ex2, xs, u2);
  }
  size_t cb = (size_t)c * H + t;
  bool any = e1 > e0;
  float v0 = any ? u0 / z0 : 0.f;
  float v1 = any ? u1 / z1 : 0.f;
  float v2 = any ? u2 / z2 : 0.f;
  unsigned short vh, vl;
  split_rne(v0, vh, vl); aggxh[0 * ((size_t)NB * H) + cb] = vh; aggxl[0 * ((size_t)NB * H) + cb] = vl;
  split_rne(v1, vh, vl); aggxh[1 * ((size_t)NB * H) + cb] = vh; aggxl[1 * ((size_t)NB * H) + cb] = vl;
  split_rne(v2, vh, vl); aggxh[2 * ((size_t)NB * H) + cb] = vh; aggxl[2 * ((size_t)NB * H) + cb] = vl;
}

// ---------------- output gather ------------------------------------------------
__global__ void scatter_out(const float* __restrict__ l2out, const int* __restrict__ sel_map,
                            const int* __restrict__ root, const int* __restrict__ aggp,
                            float* __restrict__ out) {
  int id = blockIdx.x * 256 + threadIdx.x;
  if (id >= NB * H) return;
  int b = id >> 7, f = id & 127;
  int node = root[2 * b + (aggp[0] ? 0 : 1)];
  int c = sel_map[node];
  out[id] = l2out[(size_t)c * H + f];
}

// ==============================================================================
extern "C" void kernel_launch(void* const* d_in, const int* in_sizes, int n_in,
                              void* d_out, int out_size, void* d_ws, size_t ws_size,
                              hipStream_t stream) {
  const float* node_feat = (const float*)d_in[0];
  const float* send_embd = (const float*)d_in[1];
  const int*   edge_idx  = (const int*)d_in[2];
  const int*   root_idx  = (const int*)d_in[3];
  const int*   aggp      = (const int*)d_in[4];
  const float* lin1_W    = (const float*)d_in[5];
  const float* lin1_b    = (const float*)d_in[6];
  const float* gat_W     = (const float*)d_in[7];
  const float* gat_asrc  = (const float*)d_in[8];
  const float* gat_adst  = (const float*)d_in[9];
  const float* gat_b     = (const float*)d_in[10];
  const float* lstm_Wih  = (const float*)d_in[11];
  const float* lstm_Whh  = (const float*)d_in[12];
  const float* lstm_b    = (const float*)d_in[13];
  const float* lin2_W    = (const float*)d_in[14];
  const float* lin2_b    = (const float*)d_in[15];
  float* out = (float*)d_out;

  char* ws = (char*)d_ws;
  float* x       = (float*)(ws + OFF_X);
  float* s_src   = (float*)(ws + OFF_SSRC);
  float* s_dst   = (float*)(ws + OFF_SDST);
  float* wvec    = (float*)(ws + OFF_WVEC);
  int*   sel_map = (int*)(ws + OFF_SELMAP);
  int*   nodelst = (int*)(ws + OFF_NODELST);
  int*   cnt     = (int*)(ws + OFF_CNT);
  int*   deg     = (int*)(ws + OFF_DEG);
  int*   offs    = (int*)(ws + OFF_OFFS);
  int*   cursor  = (int*)(ws + OFF_CURSOR);
  int*   esort   = (int*)(ws + OFF_ESORT);
  unsigned short* aggxh = (unsigned short*)(ws + OFF_AGGXH);
  unsigned short* aggxl = (unsigned short*)(ws + OFF_AGGXL);
  unsigned short* xsh   = (unsigned short*)(ws + OFF_XSH);
  unsigned short* xsl   = (unsigned short*)(ws + OFF_XSL);
  unsigned short* hth   = (unsigned short*)(ws + OFF_HTH);
  unsigned short* htl   = (unsigned short*)(ws + OFF_HTL);
  unsigned short* hh    = (unsigned short*)(ws + OFF_HH);
  unsigned short* hl    = (unsigned short*)(ws + OFF_HL);
  float* cbuf    = (float*)(ws + OFF_CBUF);
  float* l2out   = (float*)(ws + OFF_L2OUT);
  unsigned short* whi = (unsigned short*)(ws + OFF_WHI);
  unsigned short* wlo = (unsigned short*)(ws + OFF_WLO);

  (void)hipMemsetAsync(sel_map, 0xFF, (size_t)N * 4, stream);   // -1
  (void)hipMemsetAsync(cnt, 0, 256, stream);
  (void)hipMemsetAsync(deg, 0, NB * 4, stream);
  (void)hipMemsetAsync(cursor, 0, NB * 4, stream);
  (void)hipMemsetAsync(cbuf, 0, (size_t)NB * H * 4, stream);
  (void)hipMemsetAsync(hh, 0, (size_t)NB * H * 2, stream);      // h=0 at hop 0
  (void)hipMemsetAsync(hl, 0, (size_t)NB * H * 2, stream);

  wvec_kernel<<<6, 128, 0, stream>>>(gat_W, gat_asrc, gat_adst, wvec);
  mark_roots<<<(NB + 255) / 256, 256, 0, stream>>>(root_idx, aggp, sel_map);
  assign_ids<<<(N + 255) / 256, 256, 0, stream>>>(sel_map, nodelst, cnt);
  convert_weights<<<(WTOT + 255) / 256, 256, 0, stream>>>(lin1_W, gat_W, lstm_Wih,
                                                          lstm_Whh, lin2_W, whi, wlo);

  // lin1: x = [node_feat | send_embd] @ lin1_W + lin1_b  (M=100000, 128 cols)
  gemm_lin1<<<(N + 127) / 128, 256, 0, stream>>>(
      node_feat, send_embd, whi + WOFF_L1, wlo + WOFF_L1, lin1_b, x, N);

  score_kernel<<<(N + 3) / 4, 256, 0, stream>>>(x, wvec, s_src, s_dst);

  count_edges<<<(E + 255) / 256, 256, 0, stream>>>(edge_idx, sel_map, deg);
  scan_kernel<<<1, 1024, 0, stream>>>(deg, offs);
  scatter_edges2<<<(E + 255) / 256, 256, 0, stream>>>(edge_idx, sel_map, offs, cursor, esort);
  gat_node_kernel<<<NB, 128, 0, stream>>>(nodelst, cnt, offs, esort, x, s_src, s_dst,
                                          aggxh, aggxl, xsh, xsl);

  for (int i = 0; i < HOPS; i++) {
    // htmp = tanh(aggx_i @ gat_W[i] + gat_b[i])  -> bf16 pair
    gemm_small<<<dim3(1, NB / 64), 256, 0, stream>>>(
        aggxh + (size_t)i * NB * H, aggxl + (size_t)i * NB * H,
        whi + WOFF_GAT + i * 16384, wlo + WOFF_GAT + i * 16384,
        gat_b + (size_t)i * H, nullptr, hth, htl, H, 1);
    // fused gates GEMM + LSTM pointwise: A = [htmp | xs-or-h | h]
    const unsigned short* x1h = (i == 0) ? xsh : hh;
    const unsigned short* x1l = (i == 0) ? xsl : hl;
    lstm_fused<<<dim3(4, NB / 64), 256, 0, stream>>>(
        hth, htl, x1h, x1l, hh, hl,
        whi + WOFF_CAT + i * 196608, wlo + WOFF_CAT + i * 196608,
        lstm_b + (size_t)i * 512, cbuf, hh, hl);
  }

  // lin2: l2out = h @ lin2_W + lin2_b
  gemm_small<<<dim3(1, NB / 64), 256, 0, stream>>>(
      hh, hl, whi + WOFF_L2, wlo + WOFF_L2, lin2_b, l2out, nullptr, nullptr, H, 0);

  scatter_out<<<(NB * H + 255) / 256, 256, 0, stream>>>(l2out, sel_map, root_idx, aggp, out);
}

// Round 6
// 482.213 us; speedup vs baseline: 1.0673x; 1.0673x over previous
//
#include <hip/hip_runtime.h>

// Problem constants (match reference)
constexpr int N  = 100000;   // nodes
constexpr int E  = 1600000;  // edges
constexpr int H  = 128;      // hidden
constexpr int NB = 4096;     // root pairs
constexpr int HOPS = 3;

// Transposed converted-weight buffer (element offsets into whi/wlo ushort arrays)
// All stored n-major: Bt[n][k]. CAT block additionally gate-permuted (see prep).
constexpr int WOFF_L1  = 0;                      // [128 n][256 k] lin1_W^T
constexpr int WOFF_GAT = 32768;                  // 3 x [128][128] gat_W^T
constexpr int WOFF_CAT = 81920;                  // 3 x [512 p][384 k] perm [Wih;Whh]^T
constexpr int WOFF_L2  = 671744;                 // [128][128] lin2_W^T
constexpr int WTOT     = 688128;

// ---------------- workspace layout (byte offsets, 256B aligned) ---------------
constexpr size_t ALIGN = 256;
constexpr size_t alup(size_t x) { return (x + ALIGN - 1) & ~(ALIGN - 1); }

constexpr size_t OFF_X       = 0;                                        // [N,128] f32
constexpr size_t OFF_SSRC    = alup(OFF_X + (size_t)N * H * 4);          // [3][N] f32
constexpr size_t OFF_SDST    = alup(OFF_SSRC + (size_t)3 * N * 4);       // [3][N] f32
constexpr size_t OFF_WVEC    = alup(OFF_SDST + (size_t)3 * N * 4);       // [6][128] f32
constexpr size_t OFF_SELMAP  = alup(OFF_WVEC + 6 * H * 4);               // [N] int
constexpr size_t OFF_NODELST = alup(OFF_SELMAP + (size_t)N * 4);         // [4096] int
constexpr size_t OFF_CNT     = alup(OFF_NODELST + NB * 4);               // [64] int
constexpr size_t OFF_DEG     = alup(OFF_CNT + 256);                      // [4096] int
constexpr size_t OFF_OFFS    = alup(OFF_DEG + NB * 4);                   // [4097] int
constexpr size_t OFF_CURSOR  = alup(OFF_OFFS + (NB + 1) * 4);            // [4096] int
constexpr size_t OFF_ESORT   = alup(OFF_CURSOR + NB * 4);                // [E] int
constexpr size_t OFF_AGGXH   = alup(OFF_ESORT + (size_t)E * 4);          // [3][4096][128] us
constexpr size_t OFF_AGGXL   = alup(OFF_AGGXH + (size_t)3 * NB * H * 2);
constexpr size_t OFF_XSH     = alup(OFF_AGGXL + (size_t)3 * NB * H * 2); // [4096][128] us
constexpr size_t OFF_XSL     = alup(OFF_XSH + (size_t)NB * H * 2);
constexpr size_t OFF_HH      = alup(OFF_XSL + (size_t)NB * H * 2);       // h pair
constexpr size_t OFF_HL      = alup(OFF_HH + (size_t)NB * H * 2);
constexpr size_t OFF_CBUF    = alup(OFF_HL + (size_t)NB * H * 2);        // [4096][128] f32
constexpr size_t OFF_L2OUT   = alup(OFF_CBUF + (size_t)NB * H * 4);      // [4096][128] f32
constexpr size_t OFF_WHI     = alup(OFF_L2OUT + (size_t)NB * H * 4);     // [WTOT] us
constexpr size_t OFF_WLO     = alup(OFF_WHI + (size_t)WTOT * 2);         // [WTOT] us

__device__ __forceinline__ float lrelu(float v) { return v > 0.f ? v : 0.2f * v; }
__device__ __forceinline__ float sigmoidf_(float v) { return 1.f / (1.f + __expf(-v)); }

// RNE bf16 split (producers — off the hot path)
__device__ __forceinline__ unsigned short f2bf(float f) {
  unsigned u = __float_as_uint(f);
  unsigned r = (u + 0x7FFFu + ((u >> 16) & 1u)) >> 16;
  return (unsigned short)r;
}
__device__ __forceinline__ float bf2f(unsigned short h) {
  return __uint_as_float((unsigned)h << 16);
}
__device__ __forceinline__ void split_rne(float f, unsigned short& hi, unsigned short& lo) {
  unsigned short hh = f2bf(f);
  hi = hh;
  lo = f2bf(f - bf2f(hh));
}
// 4-op truncation split (lin1 hot path); pointer outs (vector elems can't bind refs)
__device__ __forceinline__ void split_trunc(float f, short* hi, short* lo) {
  unsigned u = __float_as_uint(f);
  *hi = (short)(u >> 16);
  float r = f - __uint_as_float(u & 0xFFFF0000u);
  *lo = (short)(__float_as_uint(r) >> 16);
}

typedef short bf16x8 __attribute__((ext_vector_type(8)));
typedef float f32x4  __attribute__((ext_vector_type(4)));

#define MFMA3(ACC, AH, AL, BH, BL)                                               \
  ACC = __builtin_amdgcn_mfma_f32_16x16x32_bf16(AH, BH, ACC, 0, 0, 0);           \
  ACC = __builtin_amdgcn_mfma_f32_16x16x32_bf16(AH, BL, ACC, 0, 0, 0);           \
  ACC = __builtin_amdgcn_mfma_f32_16x16x32_bf16(AL, BH, ACC, 0, 0, 0);

// ---------------- init: replaces 7 memsets -------------------------------------
__global__ void init_ws(int* __restrict__ sel_map, int* __restrict__ deg,
                        int* __restrict__ cursor, int* __restrict__ cnt,
                        float* __restrict__ cbuf, unsigned short* __restrict__ hh,
                        unsigned short* __restrict__ hl) {
  int i = blockIdx.x * 256 + threadIdx.x;
  int stride = gridDim.x * 256;
  for (int n = i; n < N; n += stride) sel_map[n] = -1;
  for (int n = i; n < NB; n += stride) { deg[n] = 0; cursor[n] = 0; }
  if (i < 64) cnt[i] = 0;
  for (int n = i; n < NB * H; n += stride) { cbuf[n] = 0.f; hh[n] = 0; hl[n] = 0; }
}

// ---------------- prep: wvec + weight convert (one launch) ---------------------
// blocks 0..5: wvec[i*2+which][k] = sum_j gat_W[i][k][j]*a[i][j]
// blocks 6.. : fp32 -> transposed bf16 hi/lo (CAT block gate-permuted)
__global__ void prep_kernel(const float* __restrict__ gat_W,
                            const float* __restrict__ a_src,
                            const float* __restrict__ a_dst,
                            float* __restrict__ wvec,
                            const float* __restrict__ lin1_W,
                            const float* __restrict__ Wih,
                            const float* __restrict__ Whh,
                            const float* __restrict__ lin2_W,
                            unsigned short* __restrict__ whi,
                            unsigned short* __restrict__ wlo) {
  if (blockIdx.x < 6) {
    int i = blockIdx.x >> 1, which = blockIdx.x & 1;
    int k = threadIdx.x;
    __shared__ float av[H];
    if (k < H) av[k] = which ? a_dst[i * H + k] : a_src[i * H + k];
    __syncthreads();
    if (k >= H) return;
    const float* Wr = gat_W + (size_t)i * H * H + (size_t)k * H;
    float s = 0.f;
    #pragma unroll 8
    for (int j = 0; j < H; j++) s = fmaf(Wr[j], av[j], s);
    wvec[(i * 2 + which) * H + k] = s;
    return;
  }
  int idx = (blockIdx.x - 6) * 256 + threadIdx.x;
  if (idx >= WTOT) return;
  float v;
  if (idx < WOFF_GAT) {                      // L1t [128 n][256 k]
    int n = idx >> 8, k = idx & 255;
    v = lin1_W[k * 128 + n];
  } else if (idx < WOFF_CAT) {               // GATt 3 x [128 n][128 k]
    int r = idx - WOFF_GAT;
    int hop = r >> 14, q = r & 16383;
    int n = q >> 7, k = q & 127;
    v = gat_W[hop * 16384 + k * 128 + n];
  } else if (idx < WOFF_L2) {                // CATt 3 x [512 p][384 k], gate-perm
    int r = idx - WOFF_CAT;
    int hop = r / 196608, q = r % 196608;
    int p = q / 384, k = q % 384;
    // p -> (colg, jf, g, nl): f = colg*64 + jf*16 + nl; orig col = g*128 + f
    int colg = p >> 8, jf = (p >> 6) & 3, g = (p >> 4) & 3, nlo = p & 15;
    int col = g * 128 + colg * 64 + jf * 16 + nlo;
    v = (k < 256) ? Wih[hop * 131072 + k * 512 + col]
                  : Whh[hop * 65536 + (k - 256) * 512 + col];
  } else {                                   // L2t [128 n][128 k]
    int r = idx - WOFF_L2;
    int n = r >> 7, k = r & 127;
    v = lin2_W[k * 128 + n];
  }
  unsigned short hh, ll;
  split_rne(v, hh, ll);
  whi[idx] = hh;
  wlo[idx] = ll;
}

// ---------------- roots: mark + compact-id assign in one pass ------------------
__global__ void roots_assign(const int* __restrict__ root, const int* __restrict__ aggp,
                             int* __restrict__ sel_map, int* __restrict__ node_list,
                             int* __restrict__ cnt) {
  int b = blockIdx.x * 256 + threadIdx.x;
  if (b >= NB) return;
  int node = root[2 * b + (aggp[0] ? 0 : 1)];
  int old = atomicCAS(&sel_map[node], -1, -2);
  if (old == -1) {              // winner assigns the compact id
    int c = atomicAdd(cnt, 1);
    sel_map[node] = c;          // visible to later kernels (dispatch boundary)
    node_list[c] = node;
  }
}

// ---------------- lin1: 256x128 tile, LDS-staged B, trunc-split A --------------
// 4 waves x 64 rows. B staged in 4 stages of 64 k (36 KB LDS -> 4 blocks/CU).
__global__ __launch_bounds__(256)
void gemm_lin1(const float* __restrict__ a0, const float* __restrict__ a1,
               const unsigned short* __restrict__ Bth,
               const unsigned short* __restrict__ Btl,
               const float* __restrict__ bias, float* __restrict__ Cc, int M) {
  __shared__ unsigned short Bs0[128 * 72];   // [n][k-in-stage], pitch 72 (2-way free)
  __shared__ unsigned short Bs1[128 * 72];
  const int t = threadIdx.x, lane = t & 63, wave = t >> 6;
  const int nl = lane & 15, quad = lane >> 4;
  const int rt = blockIdx.x * 256 + wave * 64;
  const float* asegs[2] = {a0, a1};

  f32x4 acc[4][8];
  #pragma unroll
  for (int i = 0; i < 4; i++)
    #pragma unroll
    for (int j = 0; j < 8; j++) acc[i][j] = (f32x4){0.f, 0.f, 0.f, 0.f};

  const int sn = t >> 1, skh = (t & 1) * 32;       // staging: thread -> (n, k-half)

  for (int st = 0; st < 4; st++) {                 // stage = 64 global k
    {
      const unsigned short* gh = Bth + sn * 256 + st * 64 + skh;
      const unsigned short* gl = Btl + sn * 256 + st * 64 + skh;
      #pragma unroll
      for (int c = 0; c < 4; c++) {
        *(bf16x8*)&Bs0[sn * 72 + skh + c * 8] = *(const bf16x8*)(gh + c * 8);
        *(bf16x8*)&Bs1[sn * 72 + skh + c * 8] = *(const bf16x8*)(gl + c * 8);
      }
    }
    __syncthreads();
    #pragma unroll
    for (int u = 0; u < 2; u++) {                  // two 32-k MFMA steps
      const int kgb = st * 64 + u * 32;
      const float* A = asegs[kgb >> 7];
      const int kseg = (kgb & 127) + quad * 8;
      bf16x8 ahi[4], alo[4];
      #pragma unroll
      for (int i = 0; i < 4; i++) {
        int row = rt + i * 16 + nl;
        float4 v0 = make_float4(0.f, 0.f, 0.f, 0.f), v1 = v0;
        if (row < M) {
          const float* p = A + (size_t)row * H + kseg;
          v0 = *(const float4*)p;
          v1 = *(const float4*)(p + 4);
        }
        float af[8] = {v0.x, v0.y, v0.z, v0.w, v1.x, v1.y, v1.z, v1.w};
        #pragma unroll
        for (int j = 0; j < 8; j++) {
          short h_, l_;
          split_trunc(af[j], &h_, &l_);
          ahi[i][j] = h_;
          alo[i][j] = l_;
        }
      }
      #pragma unroll
      for (int j = 0; j < 8; j++) {
        int off = (j * 16 + nl) * 72 + u * 32 + quad * 8;
        bf16x8 bh = *(const bf16x8*)&Bs0[off];
        bf16x8 bl = *(const bf16x8*)&Bs1[off];
        #pragma unroll
        for (int i = 0; i < 4; i++) {
          MFMA3(acc[i][j], ahi[i], alo[i], bh, bl);
        }
      }
    }
    __syncthreads();
  }
  float bv[8];
  #pragma unroll
  for (int j = 0; j < 8; j++) bv[j] = bias[j * 16 + nl];
  #pragma unroll
  for (int i = 0; i < 4; i++)
    #pragma unroll
    for (int r = 0; r < 4; r++) {
      int row = rt + i * 16 + quad * 4 + r;
      if (row < M) {
        float* cr = Cc + (size_t)row * H;
        #pragma unroll
        for (int j = 0; j < 8; j++) cr[j * 16 + nl] = acc[i][j][r] + bv[j];
      }
    }
}

// ---------------- attention score vectors: s = x @ wvec ----------------------
__global__ __launch_bounds__(256)
void score_kernel(const float* __restrict__ x, const float* __restrict__ wvec,
                  float* __restrict__ s_src, float* __restrict__ s_dst) {
  int wv = blockIdx.x * 4 + (threadIdx.x >> 6);
  int lane = threadIdx.x & 63;
  if (wv >= N) return;
  float2 v = *(const float2*)(x + (size_t)wv * H + lane * 2);
  float acc[6];
  #pragma unroll
  for (int i = 0; i < 6; i++) {
    float2 w = *(const float2*)(wvec + i * H + lane * 2);
    acc[i] = v.x * w.x + v.y * w.y;
  }
  #pragma unroll
  for (int off = 32; off > 0; off >>= 1)
    #pragma unroll
    for (int i = 0; i < 6; i++) acc[i] += __shfl_down(acc[i], off);
  if (lane == 0) {
    #pragma unroll
    for (int i = 0; i < 3; i++) {
      s_src[i * N + wv] = acc[2 * i + 0];
      s_dst[i * N + wv] = acc[2 * i + 1];
    }
  }
}

// ---------------- edge CSR by destination ------------------------------------
__global__ void count_edges(const int* __restrict__ ei, const int* __restrict__ sel_map,
                            int* __restrict__ deg) {
  int e = blockIdx.x * 256 + threadIdx.x;
  if (e >= E) return;
  int d = sel_map[ei[E + e]];
  if (d >= 0) atomicAdd(&deg[d], 1);
}

__global__ __launch_bounds__(1024)
void scan_kernel(const int* __restrict__ deg, int* __restrict__ offs) {
  __shared__ int part[1024];
  int t = threadIdx.x;
  int base = t * 4;
  int v0 = deg[base], v1 = deg[base + 1], v2 = deg[base + 2], v3 = deg[base + 3];
  int s = v0 + v1 + v2 + v3;
  part[t] = s;
  __syncthreads();
  for (int off = 1; off < 1024; off <<= 1) {
    int tmp = (t >= off) ? part[t - off] : 0;
    __syncthreads();
    part[t] += tmp;
    __syncthreads();
  }
  int run = part[t] - s;
  offs[base] = run; run += v0;
  offs[base + 1] = run; run += v1;
  offs[base + 2] = run; run += v2;
  offs[base + 3] = run; run += v3;
  if (t == 1023) offs[NB] = part[1023];
}

__global__ void scatter_edges2(const int* __restrict__ ei, const int* __restrict__ sel_map,
                               const int* __restrict__ offs, int* __restrict__ cursor,
                               int* __restrict__ es_sorted) {
  int e = blockIdx.x * 256 + threadIdx.x;
  if (e >= E) return;
  int d = sel_map[ei[E + e]];
  if (d >= 0) {
    int p = atomicAdd(&cursor[d], 1);
    es_sorted[offs[d] + p] = ei[e];
  }
}

// ---------------- per-destination GAT softmax aggregation ---------------------
__global__ __launch_bounds__(128)
void gat_node_kernel(const int* __restrict__ node_list, const int* __restrict__ cntp,
                     const int* __restrict__ offs, const int* __restrict__ es_sorted,
                     const float* __restrict__ x, const float* __restrict__ s_src,
                     const float* __restrict__ s_dst,
                     unsigned short* __restrict__ aggxh, unsigned short* __restrict__ aggxl,
                     unsigned short* __restrict__ xsh, unsigned short* __restrict__ xsl) {
  int c = blockIdx.x;
  if (c >= cntp[0]) return;
  int t = threadIdx.x;
  int n = node_list[c];
  {
    float xv = x[(size_t)n * H + t];
    unsigned short vh, vl;
    split_rne(xv, vh, vl);
    xsh[(size_t)c * H + t] = vh;
    xsl[(size_t)c * H + t] = vl;
  }
  float sd0 = s_dst[0 * N + n], sd1 = s_dst[1 * N + n], sd2 = s_dst[2 * N + n];
  int e0 = offs[c], e1 = offs[c + 1];
  float m0 = -1e30f, m1 = -1e30f, m2 = -1e30f;
  for (int e = e0 + t; e < e1; e += 128) {
    int s = es_sorted[e];
    m0 = fmaxf(m0, lrelu(s_src[0 * N + s] + sd0));
    m1 = fmaxf(m1, lrelu(s_src[1 * N + s] + sd1));
    m2 = fmaxf(m2, lrelu(s_src[2 * N + s] + sd2));
  }
  __shared__ float red[3][128];
  red[0][t] = m0; red[1][t] = m1; red[2][t] = m2;
  __syncthreads();
  for (int s2 = 64; s2 > 0; s2 >>= 1) {
    if (t < s2) {
      red[0][t] = fmaxf(red[0][t], red[0][t + s2]);
      red[1][t] = fmaxf(red[1][t], red[1][t + s2]);
      red[2][t] = fmaxf(red[2][t], red[2][t + s2]);
    }
    __syncthreads();
  }
  m0 = red[0][0]; m1 = red[1][0]; m2 = red[2][0];
  float u0 = 0.f, u1 = 0.f, u2 = 0.f, z0 = 0.f, z1 = 0.f, z2 = 0.f;
  for (int e = e0; e < e1; e++) {
    int s = es_sorted[e];
    float xs = x[(size_t)s * H + t];
    float ex0 = __expf(lrelu(s_src[0 * N + s] + sd0) - m0);
    float ex1 = __expf(lrelu(s_src[1 * N + s] + sd1) - m1);
    float ex2 = __expf(lrelu(s_src[2 * N + s] + sd2) - m2);
    z0 += ex0; z1 += ex1; z2 += ex2;
    u0 = fmaf(ex0, xs, u0); u1 = fmaf(ex1, xs, u1); u2 = fmaf(ex2, xs, u2);
  }
  size_t cb = (size_t)c * H + t;
  bool any = e1 > e0;
  float v0 = any ? u0 / z0 : 0.f;
  float v1 = any ? u1 / z1 : 0.f;
  float v2 = any ? u2 / z2 : 0.f;
  unsigned short vh, vl;
  split_rne(v0, vh, vl); aggxh[0 * ((size_t)NB * H) + cb] = vh; aggxl[0 * ((size_t)NB * H) + cb] = vl;
  split_rne(v1, vh, vl); aggxh[1 * ((size_t)NB * H) + cb] = vh; aggxl[1 * ((size_t)NB * H) + cb] = vl;
  split_rne(v2, vh, vl); aggxh[2 * ((size_t)NB * H) + cb] = vh; aggxl[2 * ((size_t)NB * H) + cb] = vl;
}

// ---------------- fused hop: htmp GEMM + gates GEMM + LSTM (+ lin2 on last) ----
// Block = 32 rows, 4 waves = 2 row-groups x 2 col-groups. All row accesses block-local.
__global__ __launch_bounds__(256)
void hop_fused(const unsigned short* __restrict__ agh, const unsigned short* __restrict__ agl,
               const unsigned short* __restrict__ gWh, const unsigned short* __restrict__ gWl,
               const float* __restrict__ gbias,
               const unsigned short* __restrict__ x1h, const unsigned short* __restrict__ x1l,
               const unsigned short* __restrict__ CWh, const unsigned short* __restrict__ CWl,
               const float* __restrict__ lbias,
               float* __restrict__ cbuf, unsigned short* __restrict__ hh,
               unsigned short* __restrict__ hl,
               const unsigned short* __restrict__ L2h, const unsigned short* __restrict__ L2l,
               const float* __restrict__ lin2_b, float* __restrict__ l2out, int do_lin2) {
  __shared__ unsigned short Hh[32 * 136];
  __shared__ unsigned short Hl[32 * 136];
  const int t = threadIdx.x, lane = t & 63, wave = t >> 6;
  const int nl = lane & 15, quad = lane >> 4;
  const int rowg = wave >> 1, colg = wave & 1;
  const int rl0 = rowg * 16;                       // local row base (wave)
  const int r0 = blockIdx.x * 32 + rl0;            // global row base (wave)

  // ---- GEMM1: htmp = tanh(aggx @ gatW + b); wave: 16 rows x 64 cols
  f32x4 acc1[4];
  #pragma unroll
  for (int j = 0; j < 4; j++) acc1[j] = (f32x4){0.f, 0.f, 0.f, 0.f};
  #pragma unroll
  for (int kt = 0; kt < 4; kt++) {
    int kk = kt * 32 + quad * 8;
    size_t aoff = (size_t)(r0 + nl) * H + kk;
    bf16x8 ah = *(const bf16x8*)(agh + aoff);
    bf16x8 al = *(const bf16x8*)(agl + aoff);
    #pragma unroll
    for (int j = 0; j < 4; j++) {
      size_t boff = (size_t)(colg * 64 + j * 16 + nl) * 128 + kk;
      bf16x8 bh = *(const bf16x8*)(gWh + boff);
      bf16x8 bl = *(const bf16x8*)(gWl + boff);
      MFMA3(acc1[j], ah, al, bh, bl);
    }
  }
  #pragma unroll
  for (int j = 0; j < 4; j++) {
    int col = colg * 64 + j * 16 + nl;
    float bv = gbias[col];
    #pragma unroll
    for (int r = 0; r < 4; r++) {
      int rl = rl0 + quad * 4 + r;
      float v = tanhf(acc1[j][r] + bv);
      unsigned short vh, vl2;
      split_rne(v, vh, vl2);
      Hh[rl * 136 + col] = vh;
      Hl[rl * 136 + col] = vl2;
    }
  }
  __syncthreads();

  // ---- GEMM2: permuted gates; wave: 16 rows x 256 perm-cols (all 4 gates/lane)
  f32x4 acc2[16];
  #pragma unroll
  for (int j = 0; j < 16; j++) acc2[j] = (f32x4){0.f, 0.f, 0.f, 0.f};
  for (int kt = 0; kt < 12; kt++) {
    int kk = (kt & 3) * 32 + quad * 8;
    bf16x8 ah, al;
    if (kt < 4) {
      ah = *(const bf16x8*)&Hh[(rl0 + nl) * 136 + kk];
      al = *(const bf16x8*)&Hl[(rl0 + nl) * 136 + kk];
    } else {
      const unsigned short* ph = (kt < 8) ? x1h : hh;
      const unsigned short* pl = (kt < 8) ? x1l : hl;
      size_t aoff = (size_t)(r0 + nl) * H + kk;
      ah = *(const bf16x8*)(ph + aoff);
      al = *(const bf16x8*)(pl + aoff);
    }
    int kg = kt * 32 + quad * 8;
    #pragma unroll
    for (int j = 0; j < 16; j++) {
      size_t boff = (size_t)(colg * 256 + j * 16 + nl) * 384 + kg;
      bf16x8 bh = *(const bf16x8*)(CWh + boff);
      bf16x8 bl = *(const bf16x8*)(CWl + boff);
      MFMA3(acc2[j], ah, al, bh, bl);
    }
  }
  __syncthreads();   // all h reads (kt 8..11) done before h writes below

  // ---- LSTM pointwise; write h pair (global + LDS for lin2)
  #pragma unroll
  for (int jf = 0; jf < 4; jf++) {
    int f = colg * 64 + jf * 16 + nl;
    float b_i = lbias[0 * 128 + f], b_f = lbias[1 * 128 + f];
    float b_g = lbias[2 * 128 + f], b_o = lbias[3 * 128 + f];
    #pragma unroll
    for (int r = 0; r < 4; r++) {
      int rl = rl0 + quad * 4 + r;
      size_t id = (size_t)(blockIdx.x * 32 + rl) * H + f;
      float gi = acc2[jf * 4 + 0][r] + b_i;
      float gf = acc2[jf * 4 + 1][r] + b_f;
      float gg = acc2[jf * 4 + 2][r] + b_g;
      float go = acc2[jf * 4 + 3][r] + b_o;
      float cp = cbuf[id];
      float cn = sigmoidf_(gf) * cp + sigmoidf_(gi) * tanhf(gg);
      float hn = sigmoidf_(go) * tanhf(cn);
      cbuf[id] = cn;
      unsigned short vh, vl2;
      split_rne(hn, vh, vl2);
      hh[id] = vh;
      hl[id] = vl2;
      if (do_lin2) { Hh[rl * 136 + f] = vh; Hl[rl * 136 + f] = vl2; }
    }
  }

  if (!do_lin2) return;
  __syncthreads();
  // ---- GEMM3: lin2 on h; wave: 16 rows x 64 cols
  f32x4 acc3[4];
  #pragma unroll
  for (int j = 0; j < 4; j++) acc3[j] = (f32x4){0.f, 0.f, 0.f, 0.f};
  #pragma unroll
  for (int kt = 0; kt < 4; kt++) {
    int kk = kt * 32 + quad * 8;
    bf16x8 ah = *(const bf16x8*)&Hh[(rl0 + nl) * 136 + kk];
    bf16x8 al = *(const bf16x8*)&Hl[(rl0 + nl) * 136 + kk];
    #pragma unroll
    for (int j = 0; j < 4; j++) {
      size_t boff = (size_t)(colg * 64 + j * 16 + nl) * 128 + kk;
      bf16x8 bh = *(const bf16x8*)(L2h + boff);
      bf16x8 bl = *(const bf16x8*)(L2l + boff);
      MFMA3(acc3[j], ah, al, bh, bl);
    }
  }
  #pragma unroll
  for (int j = 0; j < 4; j++) {
    int col = colg * 64 + j * 16 + nl;
    float bv = lin2_b[col];
    #pragma unroll
    for (int r = 0; r < 4; r++) {
      int row = blockIdx.x * 32 + rl0 + quad * 4 + r;
      l2out[(size_t)row * H + col] = acc3[j][r] + bv;
    }
  }
}

// ---------------- output gather ------------------------------------------------
__global__ void scatter_out(const float* __restrict__ l2out, const int* __restrict__ sel_map,
                            const int* __restrict__ root, const int* __restrict__ aggp,
                            float* __restrict__ out) {
  int id = blockIdx.x * 256 + threadIdx.x;
  if (id >= NB * H) return;
  int b = id >> 7, f = id & 127;
  int node = root[2 * b + (aggp[0] ? 0 : 1)];
  int c = sel_map[node];
  out[id] = l2out[(size_t)c * H + f];
}

// ==============================================================================
extern "C" void kernel_launch(void* const* d_in, const int* in_sizes, int n_in,
                              void* d_out, int out_size, void* d_ws, size_t ws_size,
                              hipStream_t stream) {
  const float* node_feat = (const float*)d_in[0];
  const float* send_embd = (const float*)d_in[1];
  const int*   edge_idx  = (const int*)d_in[2];
  const int*   root_idx  = (const int*)d_in[3];
  const int*   aggp      = (const int*)d_in[4];
  const float* lin1_W    = (const float*)d_in[5];
  const float* lin1_b    = (const float*)d_in[6];
  const float* gat_W     = (const float*)d_in[7];
  const float* gat_asrc  = (const float*)d_in[8];
  const float* gat_adst  = (const float*)d_in[9];
  const float* gat_b     = (const float*)d_in[10];
  const float* lstm_Wih  = (const float*)d_in[11];
  const float* lstm_Whh  = (const float*)d_in[12];
  const float* lstm_b    = (const float*)d_in[13];
  const float* lin2_W    = (const float*)d_in[14];
  const float* lin2_b    = (const float*)d_in[15];
  float* out = (float*)d_out;

  char* ws = (char*)d_ws;
  float* x       = (float*)(ws + OFF_X);
  float* s_src   = (float*)(ws + OFF_SSRC);
  float* s_dst   = (float*)(ws + OFF_SDST);
  float* wvec    = (float*)(ws + OFF_WVEC);
  int*   sel_map = (int*)(ws + OFF_SELMAP);
  int*   nodelst = (int*)(ws + OFF_NODELST);
  int*   cnt     = (int*)(ws + OFF_CNT);
  int*   deg     = (int*)(ws + OFF_DEG);
  int*   offs    = (int*)(ws + OFF_OFFS);
  int*   cursor  = (int*)(ws + OFF_CURSOR);
  int*   esort   = (int*)(ws + OFF_ESORT);
  unsigned short* aggxh = (unsigned short*)(ws + OFF_AGGXH);
  unsigned short* aggxl = (unsigned short*)(ws + OFF_AGGXL);
  unsigned short* xsh   = (unsigned short*)(ws + OFF_XSH);
  unsigned short* xsl   = (unsigned short*)(ws + OFF_XSL);
  unsigned short* hh    = (unsigned short*)(ws + OFF_HH);
  unsigned short* hl    = (unsigned short*)(ws + OFF_HL);
  float* cbuf    = (float*)(ws + OFF_CBUF);
  float* l2out   = (float*)(ws + OFF_L2OUT);
  unsigned short* whi = (unsigned short*)(ws + OFF_WHI);
  unsigned short* wlo = (unsigned short*)(ws + OFF_WLO);

  init_ws<<<2048, 256, 0, stream>>>(sel_map, deg, cursor, cnt, cbuf, hh, hl);
  prep_kernel<<<6 + (WTOT + 255) / 256, 256, 0, stream>>>(
      gat_W, gat_asrc, gat_adst, wvec, lin1_W, lstm_Wih, lstm_Whh, lin2_W, whi, wlo);
  roots_assign<<<(NB + 255) / 256, 256, 0, stream>>>(root_idx, aggp, sel_map, nodelst, cnt);

  // lin1: x = [node_feat | send_embd] @ lin1_W + lin1_b
  gemm_lin1<<<(N + 255) / 256, 256, 0, stream>>>(
      node_feat, send_embd, whi + WOFF_L1, wlo + WOFF_L1, lin1_b, x, N);

  score_kernel<<<(N + 3) / 4, 256, 0, stream>>>(x, wvec, s_src, s_dst);

  count_edges<<<(E + 255) / 256, 256, 0, stream>>>(edge_idx, sel_map, deg);
  scan_kernel<<<1, 1024, 0, stream>>>(deg, offs);
  scatter_edges2<<<(E + 255) / 256, 256, 0, stream>>>(edge_idx, sel_map, offs, cursor, esort);
  gat_node_kernel<<<NB, 128, 0, stream>>>(nodelst, cnt, offs, esort, x, s_src, s_dst,
                                          aggxh, aggxl, xsh, xsl);

  for (int i = 0; i < HOPS; i++) {
    const unsigned short* x1h = (i == 0) ? xsh : hh;
    const unsigned short* x1l = (i == 0) ? xsl : hl;
    hop_fused<<<NB / 32, 256, 0, stream>>>(
        aggxh + (size_t)i * NB * H, aggxl + (size_t)i * NB * H,
        whi + WOFF_GAT + i * 16384, wlo + WOFF_GAT + i * 16384,
        gat_b + (size_t)i * H,
        x1h, x1l,
        whi + WOFF_CAT + i * 196608, wlo + WOFF_CAT + i * 196608,
        lstm_b + (size_t)i * 512,
        cbuf, hh, hl,
        whi + WOFF_L2, wlo + WOFF_L2, lin2_b, l2out,
        (i == HOPS - 1) ? 1 : 0);
  }

  scatter_out<<<(NB * H + 255) / 256, 256, 0, stream>>>(l2out, sel_map, root_idx, aggp, out);
}

// Round 7
// 377.226 us; speedup vs baseline: 1.3644x; 1.2783x over previous
//
#include <hip/hip_runtime.h>

// Problem constants (match reference)
constexpr int N  = 100000;   // nodes
constexpr int E  = 1600000;  // edges
constexpr int H  = 128;      // hidden
constexpr int NB = 4096;     // root pairs
constexpr int HOPS = 3;

// Swizzled converted-weight buffer (element offsets into whi/wlo ushort arrays).
// Fragment-tile layout: tile(c,t) = 16 cols x 32 k; element (n,k) with
// n=c*16+nl, k=t*32+quad*8+e stored at (t*numC+c)*512 + (quad*16+nl)*8 + e.
// -> every B-fragment load is one coalesced dwordx4 (lane*16B).
constexpr int WOFF_L1  = 0;                      // numC=8,  numT=8  (K=256)
constexpr int WOFF_GAT = 32768;                  // 3 x numC=8,  numT=4
constexpr int WOFF_CAT = 81920;                  // 3 x numC=32, numT=12 (gate-perm)
constexpr int WOFF_L2  = 671744;                 // numC=8,  numT=4
constexpr int WTOT     = 688128;

// ---------------- workspace layout (byte offsets, 256B aligned) ---------------
constexpr size_t ALIGN = 256;
constexpr size_t alup(size_t x) { return (x + ALIGN - 1) & ~(ALIGN - 1); }

constexpr size_t OFF_X       = 0;                                        // [N,128] f32
constexpr size_t OFF_SSRC    = alup(OFF_X + (size_t)N * H * 4);          // [3][N] f32
constexpr size_t OFF_SDST    = alup(OFF_SSRC + (size_t)3 * N * 4);       // [3][N] f32
constexpr size_t OFF_WVEC    = alup(OFF_SDST + (size_t)3 * N * 4);       // [6][128] f32
constexpr size_t OFF_SELMAP  = alup(OFF_WVEC + 6 * H * 4);               // [N] int
constexpr size_t OFF_NODELST = alup(OFF_SELMAP + (size_t)N * 4);         // [4096] int
constexpr size_t OFF_CNT     = alup(OFF_NODELST + NB * 4);               // [64] int
constexpr size_t OFF_DEG     = alup(OFF_CNT + 256);                      // [4096] int
constexpr size_t OFF_OFFS    = alup(OFF_DEG + NB * 4);                   // [4097] int
constexpr size_t OFF_CURSOR  = alup(OFF_OFFS + (NB + 1) * 4);            // [4096] int
constexpr size_t OFF_ESORT   = alup(OFF_CURSOR + NB * 4);                // [E] int
constexpr size_t OFF_AGGXH   = alup(OFF_ESORT + (size_t)E * 4);          // [3][4096][128] us
constexpr size_t OFF_AGGXL   = alup(OFF_AGGXH + (size_t)3 * NB * H * 2);
constexpr size_t OFF_XSH     = alup(OFF_AGGXL + (size_t)3 * NB * H * 2); // [4096][128] us
constexpr size_t OFF_XSL     = alup(OFF_XSH + (size_t)NB * H * 2);
constexpr size_t OFF_HH      = alup(OFF_XSL + (size_t)NB * H * 2);       // h pair
constexpr size_t OFF_HL      = alup(OFF_HH + (size_t)NB * H * 2);
constexpr size_t OFF_CBUF    = alup(OFF_HL + (size_t)NB * H * 2);        // [4096][128] f32
constexpr size_t OFF_L2OUT   = alup(OFF_CBUF + (size_t)NB * H * 4);      // [4096][128] f32
constexpr size_t OFF_WHI     = alup(OFF_L2OUT + (size_t)NB * H * 4);     // [WTOT] us
constexpr size_t OFF_WLO     = alup(OFF_WHI + (size_t)WTOT * 2);         // [WTOT] us

__device__ __forceinline__ float lrelu(float v) { return v > 0.f ? v : 0.2f * v; }
__device__ __forceinline__ float sigmoidf_(float v) { return 1.f / (1.f + __expf(-v)); }

__device__ __forceinline__ unsigned short f2bf(float f) {
  unsigned u = __float_as_uint(f);
  unsigned r = (u + 0x7FFFu + ((u >> 16) & 1u)) >> 16;
  return (unsigned short)r;
}
__device__ __forceinline__ float bf2f(unsigned short h) {
  return __uint_as_float((unsigned)h << 16);
}
__device__ __forceinline__ void split_rne(float f, unsigned short& hi, unsigned short& lo) {
  unsigned short hh = f2bf(f);
  hi = hh;
  lo = f2bf(f - bf2f(hh));
}
// 4-op truncation split (lin1 hot path); pointer outs (vector elems can't bind refs)
__device__ __forceinline__ void split_trunc(float f, short* hi, short* lo) {
  unsigned u = __float_as_uint(f);
  *hi = (short)(u >> 16);
  float r = f - __uint_as_float(u & 0xFFFF0000u);
  *lo = (short)(__float_as_uint(r) >> 16);
}

typedef short bf16x8 __attribute__((ext_vector_type(8)));
typedef float f32x4  __attribute__((ext_vector_type(4)));

#define MFMA3(ACC, AH, AL, BH, BL)                                               \
  ACC = __builtin_amdgcn_mfma_f32_16x16x32_bf16(AH, BH, ACC, 0, 0, 0);           \
  ACC = __builtin_amdgcn_mfma_f32_16x16x32_bf16(AH, BL, ACC, 0, 0, 0);           \
  ACC = __builtin_amdgcn_mfma_f32_16x16x32_bf16(AL, BH, ACC, 0, 0, 0);

// ---------------- init: replaces memsets ---------------------------------------
__global__ void init_ws(int* __restrict__ sel_map, int* __restrict__ deg,
                        int* __restrict__ cursor, int* __restrict__ cnt,
                        float* __restrict__ cbuf, unsigned short* __restrict__ hh,
                        unsigned short* __restrict__ hl) {
  int i = blockIdx.x * 256 + threadIdx.x;
  int stride = gridDim.x * 256;
  for (int n = i; n < N; n += stride) sel_map[n] = -1;
  for (int n = i; n < NB; n += stride) { deg[n] = 0; cursor[n] = 0; }
  if (i < 64) cnt[i] = 0;
  for (int n = i; n < NB * H; n += stride) { cbuf[n] = 0.f; hh[n] = 0; hl[n] = 0; }
}

// ---------------- prep: wvec + weight convert to swizzled fragment tiles -------
__global__ void prep_kernel(const float* __restrict__ gat_W,
                            const float* __restrict__ a_src,
                            const float* __restrict__ a_dst,
                            float* __restrict__ wvec,
                            const float* __restrict__ lin1_W,
                            const float* __restrict__ Wih,
                            const float* __restrict__ Whh,
                            const float* __restrict__ lin2_W,
                            unsigned short* __restrict__ whi,
                            unsigned short* __restrict__ wlo) {
  if (blockIdx.x < 6) {
    int i = blockIdx.x >> 1, which = blockIdx.x & 1;
    int k = threadIdx.x;
    __shared__ float av[H];
    if (k < H) av[k] = which ? a_dst[i * H + k] : a_src[i * H + k];
    __syncthreads();
    if (k >= H) return;
    const float* Wr = gat_W + (size_t)i * H * H + (size_t)k * H;
    float s = 0.f;
    #pragma unroll 8
    for (int j = 0; j < H; j++) s = fmaf(Wr[j], av[j], s);
    wvec[(i * 2 + which) * H + k] = s;
    return;
  }
  int idx = (blockIdx.x - 6) * 256 + threadIdx.x;
  if (idx >= WTOT) return;
  float v;
  if (idx < WOFF_GAT) {                      // lin1: numC=8, K=256
    int rel = idx;
    int e = rel & 7, lane = (rel >> 3) & 63, tile = rel >> 9;
    int nl = lane & 15, quad = lane >> 4;
    int c = tile & 7, t = tile >> 3;
    int n = c * 16 + nl, k = t * 32 + quad * 8 + e;
    v = lin1_W[k * 128 + n];
  } else if (idx < WOFF_CAT) {               // gat: 3 x numC=8, K=128
    int rel = idx - WOFF_GAT;
    int hop = rel / 16384; rel %= 16384;
    int e = rel & 7, lane = (rel >> 3) & 63, tile = rel >> 9;
    int nl = lane & 15, quad = lane >> 4;
    int c = tile & 7, t = tile >> 3;
    int n = c * 16 + nl, k = t * 32 + quad * 8 + e;
    v = gat_W[hop * 16384 + k * 128 + n];
  } else if (idx < WOFF_L2) {                // CAT: 3 x numC=32, K=384, gate-perm
    int rel = idx - WOFF_CAT;
    int hop = rel / 196608; rel %= 196608;
    int e = rel & 7, lane = (rel >> 3) & 63, tile = rel >> 9;
    int nl = lane & 15, quad = lane >> 4;
    int c = tile & 31, t = tile >> 5;
    int ftile = c >> 2, g = c & 3;           // virtual col tile -> (feature-tile, gate)
    int col = g * 128 + ftile * 16 + nl;     // original column in [Wih;Whh]
    int k = t * 32 + quad * 8 + e;
    v = (k < 256) ? Wih[hop * 131072 + k * 512 + col]
                  : Whh[hop * 65536 + (k - 256) * 512 + col];
  } else {                                   // lin2: numC=8, K=128
    int rel = idx - WOFF_L2;
    int e = rel & 7, lane = (rel >> 3) & 63, tile = rel >> 9;
    int nl = lane & 15, quad = lane >> 4;
    int c = tile & 7, t = tile >> 3;
    int n = c * 16 + nl, k = t * 32 + quad * 8 + e;
    v = lin2_W[k * 128 + n];
  }
  unsigned short hh, ll;
  split_rne(v, hh, ll);
  whi[idx] = hh;
  wlo[idx] = ll;
}

// ---------------- roots: mark + compact-id assign ------------------------------
__global__ void roots_assign(const int* __restrict__ root, const int* __restrict__ aggp,
                             int* __restrict__ sel_map, int* __restrict__ node_list,
                             int* __restrict__ cnt) {
  int b = blockIdx.x * 256 + threadIdx.x;
  if (b >= NB) return;
  int node = root[2 * b + (aggp[0] ? 0 : 1)];
  int old = atomicCAS(&sel_map[node], -1, -2);
  if (old == -1) {
    int c = atomicAdd(cnt, 1);
    sel_map[node] = c;
    node_list[c] = node;
  }
}

// ---------------- lin1 (+ fused score): swizzled B, no LDS ---------------------
// Block = 4 waves x 32 rows = 128 rows, full 128 cols. A fp32 trunc-split once.
// Epilogue computes s_src/s_dst = x @ wvec via shfl_xor over the 16 nl lanes.
__global__ __launch_bounds__(256)
void gemm_lin1(const float* __restrict__ a0, const float* __restrict__ a1,
               const unsigned short* __restrict__ Bth,
               const unsigned short* __restrict__ Btl,
               const float* __restrict__ bias, float* __restrict__ Cc,
               const float* __restrict__ wvec,
               float* __restrict__ s_src, float* __restrict__ s_dst, int M) {
  const int t = threadIdx.x, lane = t & 63, wave = t >> 6;
  const int nl = lane & 15, quad = lane >> 4;
  const int rt = blockIdx.x * 128 + wave * 32;

  f32x4 acc[2][8];
  #pragma unroll
  for (int i = 0; i < 2; i++)
    #pragma unroll
    for (int c = 0; c < 8; c++) acc[i][c] = (f32x4){0.f, 0.f, 0.f, 0.f};

  #pragma unroll
  for (int kt = 0; kt < 8; kt++) {
    const float* A = (kt < 4) ? a0 : a1;
    const int kk = (kt & 3) * 32 + quad * 8;
    bf16x8 ahi[2], alo[2];
    #pragma unroll
    for (int i = 0; i < 2; i++) {
      int row = rt + i * 16 + nl;
      float4 v0 = make_float4(0.f, 0.f, 0.f, 0.f), v1 = v0;
      if (row < M) {
        const float* p = A + (size_t)row * H + kk;
        v0 = *(const float4*)p;
        v1 = *(const float4*)(p + 4);
      }
      float af[8] = {v0.x, v0.y, v0.z, v0.w, v1.x, v1.y, v1.z, v1.w};
      #pragma unroll
      for (int j = 0; j < 8; j++) {
        short h_, l_;
        split_trunc(af[j], &h_, &l_);
        ahi[i][j] = h_;
        alo[i][j] = l_;
      }
    }
    #pragma unroll
    for (int c = 0; c < 8; c++) {
      size_t boff = ((size_t)(kt * 8 + c) * 64 + lane) * 8;   // coalesced frag tile
      bf16x8 bh = *(const bf16x8*)(Bth + boff);
      bf16x8 bl = *(const bf16x8*)(Btl + boff);
      #pragma unroll
      for (int i = 0; i < 2; i++) { MFMA3(acc[i][c], ahi[i], alo[i], bh, bl); }
    }
  }

  // epilogue: bias, store x, fused score (6 dot-products vs wvec per row)
  float bv[8], wvf[6][8];
  #pragma unroll
  for (int c = 0; c < 8; c++) {
    int col = c * 16 + nl;
    bv[c] = bias[col];
    #pragma unroll
    for (int v6 = 0; v6 < 6; v6++) wvf[v6][c] = wvec[v6 * 128 + col];
  }
  #pragma unroll
  for (int i = 0; i < 2; i++)
    #pragma unroll
    for (int r = 0; r < 4; r++) {
      int row = rt + i * 16 + quad * 4 + r;
      if (row >= M) continue;
      float* cr = Cc + (size_t)row * H;
      float sc[6] = {0.f, 0.f, 0.f, 0.f, 0.f, 0.f};
      #pragma unroll
      for (int c = 0; c < 8; c++) {
        float val = acc[i][c][r] + bv[c];
        cr[c * 16 + nl] = val;
        #pragma unroll
        for (int v6 = 0; v6 < 6; v6++) sc[v6] = fmaf(val, wvf[v6][c], sc[v6]);
      }
      #pragma unroll
      for (int m = 1; m < 16; m <<= 1)
        #pragma unroll
        for (int v6 = 0; v6 < 6; v6++) sc[v6] += __shfl_xor(sc[v6], m);
      if (nl == 0) {
        #pragma unroll
        for (int h3 = 0; h3 < 3; h3++) {
          s_src[h3 * N + row] = sc[2 * h3 + 0];
          s_dst[h3 * N + row] = sc[2 * h3 + 1];
        }
      }
    }
}

// ---------------- edge CSR by destination ------------------------------------
__global__ void count_edges(const int* __restrict__ ei, const int* __restrict__ sel_map,
                            int* __restrict__ deg) {
  int e = blockIdx.x * 256 + threadIdx.x;
  if (e >= E) return;
  int d = sel_map[ei[E + e]];
  if (d >= 0) atomicAdd(&deg[d], 1);
}

__global__ __launch_bounds__(1024)
void scan_kernel(const int* __restrict__ deg, int* __restrict__ offs) {
  __shared__ int part[1024];
  int t = threadIdx.x;
  int base = t * 4;
  int v0 = deg[base], v1 = deg[base + 1], v2 = deg[base + 2], v3 = deg[base + 3];
  int s = v0 + v1 + v2 + v3;
  part[t] = s;
  __syncthreads();
  for (int off = 1; off < 1024; off <<= 1) {
    int tmp = (t >= off) ? part[t - off] : 0;
    __syncthreads();
    part[t] += tmp;
    __syncthreads();
  }
  int run = part[t] - s;
  offs[base] = run; run += v0;
  offs[base + 1] = run; run += v1;
  offs[base + 2] = run; run += v2;
  offs[base + 3] = run; run += v3;
  if (t == 1023) offs[NB] = part[1023];
}

__global__ void scatter_edges2(const int* __restrict__ ei, const int* __restrict__ sel_map,
                               const int* __restrict__ offs, int* __restrict__ cursor,
                               int* __restrict__ es_sorted) {
  int e = blockIdx.x * 256 + threadIdx.x;
  if (e >= E) return;
  int d = sel_map[ei[E + e]];
  if (d >= 0) {
    int p = atomicAdd(&cursor[d], 1);
    es_sorted[offs[d] + p] = ei[e];
  }
}

// ---------------- per-destination GAT softmax aggregation ---------------------
__global__ __launch_bounds__(128)
void gat_node_kernel(const int* __restrict__ node_list, const int* __restrict__ cntp,
                     const int* __restrict__ offs, const int* __restrict__ es_sorted,
                     const float* __restrict__ x, const float* __restrict__ s_src,
                     const float* __restrict__ s_dst,
                     unsigned short* __restrict__ aggxh, unsigned short* __restrict__ aggxl,
                     unsigned short* __restrict__ xsh, unsigned short* __restrict__ xsl) {
  int c = blockIdx.x;
  if (c >= cntp[0]) return;
  int t = threadIdx.x;
  int n = node_list[c];
  {
    float xv = x[(size_t)n * H + t];
    unsigned short vh, vl;
    split_rne(xv, vh, vl);
    xsh[(size_t)c * H + t] = vh;
    xsl[(size_t)c * H + t] = vl;
  }
  float sd0 = s_dst[0 * N + n], sd1 = s_dst[1 * N + n], sd2 = s_dst[2 * N + n];
  int e0 = offs[c], e1 = offs[c + 1];
  float m0 = -1e30f, m1 = -1e30f, m2 = -1e30f;
  for (int e = e0 + t; e < e1; e += 128) {
    int s = es_sorted[e];
    m0 = fmaxf(m0, lrelu(s_src[0 * N + s] + sd0));
    m1 = fmaxf(m1, lrelu(s_src[1 * N + s] + sd1));
    m2 = fmaxf(m2, lrelu(s_src[2 * N + s] + sd2));
  }
  __shared__ float red[3][128];
  red[0][t] = m0; red[1][t] = m1; red[2][t] = m2;
  __syncthreads();
  for (int s2 = 64; s2 > 0; s2 >>= 1) {
    if (t < s2) {
      red[0][t] = fmaxf(red[0][t], red[0][t + s2]);
      red[1][t] = fmaxf(red[1][t], red[1][t + s2]);
      red[2][t] = fmaxf(red[2][t], red[2][t + s2]);
    }
    __syncthreads();
  }
  m0 = red[0][0]; m1 = red[1][0]; m2 = red[2][0];
  float u0 = 0.f, u1 = 0.f, u2 = 0.f, z0 = 0.f, z1 = 0.f, z2 = 0.f;
  for (int e = e0; e < e1; e++) {
    int s = es_sorted[e];
    float xs = x[(size_t)s * H + t];
    float ex0 = __expf(lrelu(s_src[0 * N + s] + sd0) - m0);
    float ex1 = __expf(lrelu(s_src[1 * N + s] + sd1) - m1);
    float ex2 = __expf(lrelu(s_src[2 * N + s] + sd2) - m2);
    z0 += ex0; z1 += ex1; z2 += ex2;
    u0 = fmaf(ex0, xs, u0); u1 = fmaf(ex1, xs, u1); u2 = fmaf(ex2, xs, u2);
  }
  size_t cb = (size_t)c * H + t;
  bool any = e1 > e0;
  float v0 = any ? u0 / z0 : 0.f;
  float v1 = any ? u1 / z1 : 0.f;
  float v2 = any ? u2 / z2 : 0.f;
  unsigned short vh, vl;
  split_rne(v0, vh, vl); aggxh[0 * ((size_t)NB * H) + cb] = vh; aggxl[0 * ((size_t)NB * H) + cb] = vl;
  split_rne(v1, vh, vl); aggxh[1 * ((size_t)NB * H) + cb] = vh; aggxl[1 * ((size_t)NB * H) + cb] = vl;
  split_rne(v2, vh, vl); aggxh[2 * ((size_t)NB * H) + cb] = vh; aggxl[2 * ((size_t)NB * H) + cb] = vl;
}

// ---------------- fused hop: 16-row blocks (grid 256), swizzled weights --------
// Wave w owns feature-tiles {2w, 2w+1} (32 features, all 4 gates each).
__global__ __launch_bounds__(256)
void hop_fused(const unsigned short* __restrict__ agh, const unsigned short* __restrict__ agl,
               const unsigned short* __restrict__ gWh, const unsigned short* __restrict__ gWl,
               const float* __restrict__ gbias,
               const unsigned short* __restrict__ x1h, const unsigned short* __restrict__ x1l,
               const unsigned short* __restrict__ CWh, const unsigned short* __restrict__ CWl,
               const float* __restrict__ lbias,
               float* __restrict__ cbuf, unsigned short* __restrict__ hh,
               unsigned short* __restrict__ hl,
               const unsigned short* __restrict__ L2h, const unsigned short* __restrict__ L2l,
               const float* __restrict__ lin2_b, float* __restrict__ l2out, int do_lin2) {
  __shared__ unsigned short Hh[16 * 136];
  __shared__ unsigned short Hl[16 * 136];
  const int t = threadIdx.x, lane = t & 63, wave = t >> 6;
  const int nl = lane & 15, quad = lane >> 4;
  const int r0 = blockIdx.x * 16;

  // ---- GEMM1: htmp = tanh(aggx @ gatW + b); wave: 16 rows x 32 cols
  f32x4 acc1[2];
  #pragma unroll
  for (int j = 0; j < 2; j++) acc1[j] = (f32x4){0.f, 0.f, 0.f, 0.f};
  #pragma unroll
  for (int kt = 0; kt < 4; kt++) {
    size_t aoff = (size_t)(r0 + nl) * H + kt * 32 + quad * 8;
    bf16x8 ah = *(const bf16x8*)(agh + aoff);
    bf16x8 al = *(const bf16x8*)(agl + aoff);
    #pragma unroll
    for (int j = 0; j < 2; j++) {
      size_t boff = ((size_t)(kt * 8 + 2 * wave + j) * 64 + lane) * 8;
      bf16x8 bh = *(const bf16x8*)(gWh + boff);
      bf16x8 bl = *(const bf16x8*)(gWl + boff);
      MFMA3(acc1[j], ah, al, bh, bl);
    }
  }
  #pragma unroll
  for (int j = 0; j < 2; j++) {
    int col = wave * 32 + j * 16 + nl;
    float bv = gbias[col];
    #pragma unroll
    for (int r = 0; r < 4; r++) {
      int rl = quad * 4 + r;
      float v = tanhf(acc1[j][r] + bv);
      unsigned short vh, vl2;
      split_rne(v, vh, vl2);
      Hh[rl * 136 + col] = vh;
      Hl[rl * 136 + col] = vl2;
    }
  }
  __syncthreads();

  // ---- GEMM2: permuted gates [16 x 384] @ [384 x 512]; wave: 8 col-tiles
  f32x4 acc2[8];
  #pragma unroll
  for (int j = 0; j < 8; j++) acc2[j] = (f32x4){0.f, 0.f, 0.f, 0.f};
  for (int kt = 0; kt < 12; kt++) {
    int kk = (kt & 3) * 32 + quad * 8;
    bf16x8 ah, al;
    if (kt < 4) {
      ah = *(const bf16x8*)&Hh[nl * 136 + kk];
      al = *(const bf16x8*)&Hl[nl * 136 + kk];
    } else {
      const unsigned short* ph = (kt < 8) ? x1h : hh;
      const unsigned short* pl = (kt < 8) ? x1l : hl;
      size_t aoff = (size_t)(r0 + nl) * H + kk;
      ah = *(const bf16x8*)(ph + aoff);
      al = *(const bf16x8*)(pl + aoff);
    }
    #pragma unroll
    for (int cc = 0; cc < 8; cc++) {
      size_t boff = ((size_t)(kt * 32 + 8 * wave + cc) * 64 + lane) * 8;
      bf16x8 bh = *(const bf16x8*)(CWh + boff);
      bf16x8 bl = *(const bf16x8*)(CWl + boff);
      MFMA3(acc2[cc], ah, al, bh, bl);
    }
  }
  __syncthreads();   // all LDS + global-h reads done before h/LDS writes below

  // ---- LSTM pointwise; lane has all 4 gates of its features
  #pragma unroll
  for (int ft = 0; ft < 2; ft++) {
    int f = (2 * wave + ft) * 16 + nl;
    float b_i = lbias[0 * 128 + f], b_f = lbias[1 * 128 + f];
    float b_g = lbias[2 * 128 + f], b_o = lbias[3 * 128 + f];
    #pragma unroll
    for (int r = 0; r < 4; r++) {
      int rl = quad * 4 + r;
      size_t id = (size_t)(r0 + rl) * H + f;
      float gi = acc2[ft * 4 + 0][r] + b_i;
      float gf = acc2[ft * 4 + 1][r] + b_f;
      float gg = acc2[ft * 4 + 2][r] + b_g;
      float go = acc2[ft * 4 + 3][r] + b_o;
      float cp = cbuf[id];
      float cn = sigmoidf_(gf) * cp + sigmoidf_(gi) * tanhf(gg);
      float hn = sigmoidf_(go) * tanhf(cn);
      cbuf[id] = cn;
      unsigned short vh, vl2;
      split_rne(hn, vh, vl2);
      hh[id] = vh;
      hl[id] = vl2;
      if (do_lin2) { Hh[rl * 136 + f] = vh; Hl[rl * 136 + f] = vl2; }
    }
  }

  if (!do_lin2) return;
  __syncthreads();
  // ---- GEMM3: lin2 on h; wave: 16 rows x 32 cols
  f32x4 acc3[2];
  #pragma unroll
  for (int j = 0; j < 2; j++) acc3[j] = (f32x4){0.f, 0.f, 0.f, 0.f};
  #pragma unroll
  for (int kt = 0; kt < 4; kt++) {
    int kk = kt * 32 + quad * 8;
    bf16x8 ah = *(const bf16x8*)&Hh[nl * 136 + kk];
    bf16x8 al = *(const bf16x8*)&Hl[nl * 136 + kk];
    #pragma unroll
    for (int j = 0; j < 2; j++) {
      size_t boff = ((size_t)(kt * 8 + 2 * wave + j) * 64 + lane) * 8;
      bf16x8 bh = *(const bf16x8*)(L2h + boff);
      bf16x8 bl = *(const bf16x8*)(L2l + boff);
      MFMA3(acc3[j], ah, al, bh, bl);
    }
  }
  #pragma unroll
  for (int j = 0; j < 2; j++) {
    int col = wave * 32 + j * 16 + nl;
    float bv = lin2_b[col];
    #pragma unroll
    for (int r = 0; r < 4; r++) {
      int row = r0 + quad * 4 + r;
      l2out[(size_t)row * H + col] = acc3[j][r] + bv;
    }
  }
}

// ---------------- output gather ------------------------------------------------
__global__ void scatter_out(const float* __restrict__ l2out, const int* __restrict__ sel_map,
                            const int* __restrict__ root, const int* __restrict__ aggp,
                            float* __restrict__ out) {
  int id = blockIdx.x * 256 + threadIdx.x;
  if (id >= NB * H) return;
  int b = id >> 7, f = id & 127;
  int node = root[2 * b + (aggp[0] ? 0 : 1)];
  int c = sel_map[node];
  out[id] = l2out[(size_t)c * H + f];
}

// ==============================================================================
extern "C" void kernel_launch(void* const* d_in, const int* in_sizes, int n_in,
                              void* d_out, int out_size, void* d_ws, size_t ws_size,
                              hipStream_t stream) {
  const float* node_feat = (const float*)d_in[0];
  const float* send_embd = (const float*)d_in[1];
  const int*   edge_idx  = (const int*)d_in[2];
  const int*   root_idx  = (const int*)d_in[3];
  const int*   aggp      = (const int*)d_in[4];
  const float* lin1_W    = (const float*)d_in[5];
  const float* lin1_b    = (const float*)d_in[6];
  const float* gat_W     = (const float*)d_in[7];
  const float* gat_asrc  = (const float*)d_in[8];
  const float* gat_adst  = (const float*)d_in[9];
  const float* gat_b     = (const float*)d_in[10];
  const float* lstm_Wih  = (const float*)d_in[11];
  const float* lstm_Whh  = (const float*)d_in[12];
  const float* lstm_b    = (const float*)d_in[13];
  const float* lin2_W    = (const float*)d_in[14];
  const float* lin2_b    = (const float*)d_in[15];
  float* out = (float*)d_out;

  char* ws = (char*)d_ws;
  float* x       = (float*)(ws + OFF_X);
  float* s_src   = (float*)(ws + OFF_SSRC);
  float* s_dst   = (float*)(ws + OFF_SDST);
  float* wvec    = (float*)(ws + OFF_WVEC);
  int*   sel_map = (int*)(ws + OFF_SELMAP);
  int*   nodelst = (int*)(ws + OFF_NODELST);
  int*   cnt     = (int*)(ws + OFF_CNT);
  int*   deg     = (int*)(ws + OFF_DEG);
  int*   offs    = (int*)(ws + OFF_OFFS);
  int*   cursor  = (int*)(ws + OFF_CURSOR);
  int*   esort   = (int*)(ws + OFF_ESORT);
  unsigned short* aggxh = (unsigned short*)(ws + OFF_AGGXH);
  unsigned short* aggxl = (unsigned short*)(ws + OFF_AGGXL);
  unsigned short* xsh   = (unsigned short*)(ws + OFF_XSH);
  unsigned short* xsl   = (unsigned short*)(ws + OFF_XSL);
  unsigned short* hh    = (unsigned short*)(ws + OFF_HH);
  unsigned short* hl    = (unsigned short*)(ws + OFF_HL);
  float* cbuf    = (float*)(ws + OFF_CBUF);
  float* l2out   = (float*)(ws + OFF_L2OUT);
  unsigned short* whi = (unsigned short*)(ws + OFF_WHI);
  unsigned short* wlo = (unsigned short*)(ws + OFF_WLO);

  init_ws<<<2048, 256, 0, stream>>>(sel_map, deg, cursor, cnt, cbuf, hh, hl);
  prep_kernel<<<6 + (WTOT + 255) / 256, 256, 0, stream>>>(
      gat_W, gat_asrc, gat_adst, wvec, lin1_W, lstm_Wih, lstm_Whh, lin2_W, whi, wlo);
  roots_assign<<<(NB + 255) / 256, 256, 0, stream>>>(root_idx, aggp, sel_map, nodelst, cnt);

  // lin1 + fused score
  gemm_lin1<<<(N + 127) / 128, 256, 0, stream>>>(
      node_feat, send_embd, whi + WOFF_L1, wlo + WOFF_L1, lin1_b, x,
      wvec, s_src, s_dst, N);

  count_edges<<<(E + 255) / 256, 256, 0, stream>>>(edge_idx, sel_map, deg);
  scan_kernel<<<1, 1024, 0, stream>>>(deg, offs);
  scatter_edges2<<<(E + 255) / 256, 256, 0, stream>>>(edge_idx, sel_map, offs, cursor, esort);
  gat_node_kernel<<<NB, 128, 0, stream>>>(nodelst, cnt, offs, esort, x, s_src, s_dst,
                                          aggxh, aggxl, xsh, xsl);

  for (int i = 0; i < HOPS; i++) {
    const unsigned short* x1h = (i == 0) ? xsh : hh;
    const unsigned short* x1l = (i == 0) ? xsl : hl;
    hop_fused<<<NB / 16, 256, 0, stream>>>(
        aggxh + (size_t)i * NB * H, aggxl + (size_t)i * NB * H,
        whi + WOFF_GAT + i * 16384, wlo + WOFF_GAT + i * 16384,
        gat_b + (size_t)i * H,
        x1h, x1l,
        whi + WOFF_CAT + i * 196608, wlo + WOFF_CAT + i * 196608,
        lstm_b + (size_t)i * 512,
        cbuf, hh, hl,
        whi + WOFF_L2, wlo + WOFF_L2, lin2_b, l2out,
        (i == HOPS - 1) ? 1 : 0);
  }

  scatter_out<<<(NB * H + 255) / 256, 256, 0, stream>>>(l2out, sel_map, root_idx, aggp, out);
}